// Round 1
// baseline (1632.432 us; speedup 1.0000x reference)
//
#include <hip/hip_runtime.h>
#include <stdint.h>

#define T_STEPS 2048
#define BB 64
#define CC 128
#define HH 256
#define NCLS 10

// ws layout:
//   s1 fp32 [T][B][C]    : 2048*64*128*4 = 67108864 B
//   s2 bytes [T][B][32]  : 2048*64*32    =  4194304 B   (bit j of byte k -> h = 8k+j)
//   u3 fp32 [T][NC][B]   : 2048*10*64*4  =  5242880 B
#define S1_OFF 0
#define S2_OFF 67108864
#define U3_OFF 71303168

// ---------------- K1: conv1d(1->128,K=7,pad=3) + LIF1, t-chunked ----------------
// grid (16 chunks, 64 b), block 128 (c). chunk=128 steps, warmup=64.
__global__ __launch_bounds__(128) void k1_conv_lif1(
    const float* __restrict__ x, const float* __restrict__ cw,
    float* __restrict__ s1) {
  const int c = threadIdx.x;
  const int b = blockIdx.y;
  const int t0 = blockIdx.x * 128;
  const int ts = t0 - 64;

  float w[7];
#pragma unroll
  for (int k = 0; k < 7; ++k) w[k] = cw[c * 7 + k];

  const float* xb = x + b * 2048;
  float xw[7];
#pragma unroll
  for (int k = 0; k < 7; ++k) {
    int l = ts + k - 3;
    xw[k] = (l >= 0 && l < 2048) ? xb[l] : 0.0f;
  }

  float v = 0.0f;
  for (int t = ts; t < t0 + 128; ++t) {
    // conv at step t (window = x[t-3..t+3])
    float u = fmaf(w[0], xw[0],
              fmaf(w[1], xw[1],
              fmaf(w[2], xw[2],
              fmaf(w[3], xw[3],
              fmaf(w[4], xw[4],
              fmaf(w[5], xw[5], w[6] * xw[6]))))));
    // LIF: v = v*0.5 + u  (v*0.5 exact -> fmaf == ref's mul-then-add)
    v = fmaf(v, 0.5f, u);
    bool sp = (v >= 1.0f);
    if (t >= t0) s1[((size_t)t * BB + b) * CC + c] = sp ? 1.0f : 0.0f;
    if (sp) v = 0.0f;
    // slide window
#pragma unroll
    for (int k = 0; k < 6; ++k) xw[k] = xw[k + 1];
    int ln = t + 4;
    xw[6] = (ln >= 0 && ln < 2048) ? xb[ln] : 0.0f;
  }
}

// ---------------- K2: fused (s1 @ W1^T) + LIF2 -> s2 bits -------------------
// grid (8 h-groups, 64 b), block 256. thread: h = hg*32 + tid/8, c-chunk = (tid%8)*16.
// Sequential over all 2048 steps; u2 never materialized. All 8 lanes of a
// c-group hold identical v2 after the butterfly (IEEE add commutes).
__global__ __launch_bounds__(256) void k2_gemm2_lif2(
    const float* __restrict__ s1, const float* __restrict__ W1,
    unsigned char* __restrict__ s2) {
  const int tid  = threadIdx.x;
  const int hg   = blockIdx.x;       // 0..7
  const int b    = blockIdx.y;       // 0..63
  const int hl   = tid >> 3;         // 0..31
  const int h    = hg * 32 + hl;
  const int cc4  = (tid & 7) * 4;    // float4 index of c-chunk start
  const int lane = tid & 63;
  const int wv   = tid >> 6;         // wave 0..3

  float w[16];
#pragma unroll
  for (int j = 0; j < 16; ++j) w[j] = W1[h * CC + cc4 * 4 + j];

  const float4* s1v = (const float4*)s1;
  // row base (in float4 units) for step t: (t*64 + b)*32 + cc4
  size_t rb = ((size_t)0 * BB + b) * 32 + cc4;
  float4 c0 = s1v[rb], c1 = s1v[rb + 1], c2 = s1v[rb + 2], c3 = s1v[rb + 3];

  float v = 0.0f;
  for (int t = 0; t < T_STEPS; ++t) {
    int tn = (t < T_STEPS - 1) ? t + 1 : t;
    size_t rn = ((size_t)tn * BB + b) * 32 + cc4;
    float4 n0 = s1v[rn], n1 = s1v[rn + 1], n2 = s1v[rn + 2], n3 = s1v[rn + 3];

    float a0 = c0.x * w[0];
    a0 = fmaf(c0.y, w[1], a0);
    a0 = fmaf(c0.z, w[2], a0);
    a0 = fmaf(c0.w, w[3], a0);
    a0 = fmaf(c1.x, w[4], a0);
    a0 = fmaf(c1.y, w[5], a0);
    a0 = fmaf(c1.z, w[6], a0);
    a0 = fmaf(c1.w, w[7], a0);
    float a1 = c2.x * w[8];
    a1 = fmaf(c2.y, w[9],  a1);
    a1 = fmaf(c2.z, w[10], a1);
    a1 = fmaf(c2.w, w[11], a1);
    a1 = fmaf(c3.x, w[12], a1);
    a1 = fmaf(c3.y, w[13], a1);
    a1 = fmaf(c3.z, w[14], a1);
    a1 = fmaf(c3.w, w[15], a1);
    float u = a0 + a1;

    u += __shfl_xor(u, 1);
    u += __shfl_xor(u, 2);
    u += __shfl_xor(u, 4);

    v = fmaf(v, 0.5f, u);
    bool sp = (v >= 1.0f);
    unsigned long long m = __ballot(sp);
    if (sp) v = 0.0f;
    if (lane == 0) {
      // gather bit of lanes 0,8,..,56 -> byte (bit j <- lane 8j)
      unsigned int byte = (unsigned int)(((m & 0x0101010101010101ull) *
                                          0x0102040810204080ull) >> 56);
      s2[((size_t)t * BB + b) * 32 + (hg * 4 + wv)] = (unsigned char)byte;
    }
    c0 = n0; c1 = n1; c2 = n2; c3 = n3;
  }
}

// ---------------- K3: u3 = s2bits @ W2^T, parallel over (t,b) ----------------
// grid 512, block 256: t = blk*4 + tid/64, b = tid%64 (coalesced s2 loads and u3 stores)
__global__ __launch_bounds__(256) void k3_gemm3(
    const unsigned char* __restrict__ s2, const float* __restrict__ W2,
    float* __restrict__ u3) {
  const int tid = threadIdx.x;
  const int b = tid & 63;
  const int t = blockIdx.x * 4 + (tid >> 6);

  const uint4* p = (const uint4*)(s2 + ((size_t)t * BB + b) * 32);
  uint4 q0 = p[0], q1 = p[1];
  unsigned int wd[8] = {q0.x, q0.y, q0.z, q0.w, q1.x, q1.y, q1.z, q1.w};

  float acc[NCLS];
#pragma unroll
  for (int n = 0; n < NCLS; ++n) acc[n] = 0.0f;

#pragma unroll
  for (int wi = 0; wi < 8; ++wi) {
    unsigned int u = wd[wi];
    for (int pb = 0; pb < 32; ++pb) {   // bit pb of word wi -> h = 32*wi + pb
      float f = (float)((u >> pb) & 1u);
      int h = wi * 32 + pb;
#pragma unroll
      for (int n = 0; n < NCLS; ++n)
        acc[n] = fmaf(f, W2[n * HH + h], acc[n]);  // W2 index wave-uniform -> s_load
    }
  }
#pragma unroll
  for (int n = 0; n < NCLS; ++n)
    u3[((size_t)t * NCLS + n) * BB + b] = acc[n];
}

// ---------------- K4: LIF3 + spike count, t-chunked ----------------
// grid (10 nc, 8 chunks), block 64 (b). chunk=256 steps, warmup=64 (decay 0.5^64 -> exact).
__global__ __launch_bounds__(64) void k4_lif3(
    const float* __restrict__ u3, float* __restrict__ out) {
  const int b  = threadIdx.x;
  const int nc = blockIdx.x;
  const int t0 = blockIdx.y * 256;

  float v = 0.0f, cnt = 0.0f;
#pragma unroll 8
  for (int t = t0 - 64; t < t0 + 256; ++t) {
    float u = 0.0f;
    if (t >= 0) u = u3[((size_t)t * NCLS + nc) * BB + b];
    v = fmaf(v, 0.5f, u);
    bool sp = (v >= 1.0f);
    if (sp && t >= t0) cnt += 1.0f;
    if (sp) v = 0.0f;
  }
  atomicAdd(&out[b * NCLS + nc], cnt * (1.0f / 2048.0f));  // exact dyadic sums
}

extern "C" void kernel_launch(void* const* d_in, const int* in_sizes, int n_in,
                              void* d_out, int out_size, void* d_ws, size_t ws_size,
                              hipStream_t stream) {
  const float* x  = (const float*)d_in[0];   // [64,2048]
  const float* cw = (const float*)d_in[1];   // [128,1,7]
  const float* W1 = (const float*)d_in[2];   // [256,128]
  const float* W2 = (const float*)d_in[3];   // [10,256]
  float* out = (float*)d_out;                // [64,10]

  char* ws = (char*)d_ws;
  float*         s1 = (float*)(ws + S1_OFF);
  unsigned char* s2 = (unsigned char*)(ws + S2_OFF);
  float*         u3 = (float*)(ws + U3_OFF);

  hipMemsetAsync(d_out, 0, 64 * NCLS * sizeof(float), stream);

  k1_conv_lif1<<<dim3(16, 64), 128, 0, stream>>>(x, cw, s1);
  k2_gemm2_lif2<<<dim3(8, 64), 256, 0, stream>>>(s1, W1, s2);
  k3_gemm3<<<dim3(512), 256, 0, stream>>>(s2, W2, u3);
  k4_lif3<<<dim3(NCLS, 8), 64, 0, stream>>>(u3, out);
  (void)in_sizes; (void)n_in; (void)out_size; (void)ws_size;
}

// Round 2
// 476.855 us; speedup vs baseline: 3.4233x; 3.4233x over previous
//
#include <hip/hip_runtime.h>
#include <stdint.h>

#define T_STEPS 2048
#define BB 64
#define CC 128
#define HH 256
#define NCLS 10

// ws layout:
//   s1 fp32 [T][B][C]    : 2048*64*128*4 = 67108864 B
//   s2 bytes [T][B][32]  : 2048*64*32    =  4194304 B   (bit j of byte k -> h = 8k+j)
//   u3 fp32 [T][NC][B]   : 2048*10*64*4  =  5242880 B
#define S1_OFF 0
#define S2_OFF 67108864
#define U3_OFF 71303168

// ---------------- K1: conv1d(1->128,K=7,pad=3) + LIF1, t-chunked ----------------
// grid (16 chunks, 64 b), block 128 (c). chunk=128 steps, warmup=64.
__global__ __launch_bounds__(128) void k1_conv_lif1(
    const float* __restrict__ x, const float* __restrict__ cw,
    float* __restrict__ s1) {
  const int c = threadIdx.x;
  const int b = blockIdx.y;
  const int t0 = blockIdx.x * 128;
  const int ts = t0 - 64;

  float w[7];
#pragma unroll
  for (int k = 0; k < 7; ++k) w[k] = cw[c * 7 + k];

  const float* xb = x + b * 2048;
  float xw[7];
#pragma unroll
  for (int k = 0; k < 7; ++k) {
    int l = ts + k - 3;
    xw[k] = (l >= 0 && l < 2048) ? xb[l] : 0.0f;
  }

  float v = 0.0f;
  for (int t = ts; t < t0 + 128; ++t) {
    float u = fmaf(w[0], xw[0],
              fmaf(w[1], xw[1],
              fmaf(w[2], xw[2],
              fmaf(w[3], xw[3],
              fmaf(w[4], xw[4],
              fmaf(w[5], xw[5], w[6] * xw[6]))))));
    v = fmaf(v, 0.5f, u);             // v*0.5 exact -> fmaf == ref's mul-then-add
    bool sp = (v >= 1.0f);
    if (t >= t0) s1[((size_t)t * BB + b) * CC + c] = sp ? 1.0f : 0.0f;
    if (sp) v = 0.0f;
#pragma unroll
    for (int k = 0; k < 6; ++k) xw[k] = xw[k + 1];
    int ln = t + 4;
    xw[6] = (ln >= 0 && ln < 2048) ? xb[ln] : 0.0f;
  }
}

// ---------------- K2: fused (s1 @ W1^T) + LIF2 -> s2 bits, t-chunked -----------
// grid (2 hg, 64 b, 8 chunks), block 256 (4 waves).
// Thread = 4 h x 16 c: lane = hq*8+cg; hq=0..7 (h-quad), cg=0..7 (c-group of 16).
// h0 = hg*128 + wave*32 + hq*4.  c-chunk = cg*16.
// Chunk = 256 steps + 64-step speculative warmup (decay 0.5^64 -> exact resync;
// any spike hard-resets v to 0 -- same scheme validated in K1/K4, absmax 0).
// 8-lane xor-butterfly reduce -> all 8 c-lanes hold identical sums (IEEE add
// on identical operand pairs). Spike nibble + shfl_xor(8) -> byte store.
__global__ __launch_bounds__(256, 4) void k2_gemm2_lif2(
    const float* __restrict__ s1, const float* __restrict__ W1,
    unsigned char* __restrict__ s2) {
  const int tid  = threadIdx.x;
  const int lane = tid & 63;
  const int wv   = tid >> 6;        // 0..3
  const int cg   = lane & 7;        // 0..7  c-group
  const int hq   = lane >> 3;       // 0..7  h-quad within wave
  const int hg   = blockIdx.x;      // 0..1
  const int b    = blockIdx.y;      // 0..63
  const int t0   = blockIdx.z * 256;
  const int h0   = hg * 128 + wv * 32 + hq * 4;
  const int cb   = cg * 16;

  float w[64];
#pragma unroll
  for (int j = 0; j < 4; ++j) {
    const float4* wp = (const float4*)(W1 + (size_t)(h0 + j) * CC + cb);
#pragma unroll
    for (int k = 0; k < 4; ++k) {
      float4 f = wp[k];
      w[j * 16 + 4 * k + 0] = f.x;
      w[j * 16 + 4 * k + 1] = f.y;
      w[j * 16 + 4 * k + 2] = f.z;
      w[j * 16 + 4 * k + 3] = f.w;
    }
  }

  int ts = t0 - 64;
  if (ts < 0) ts = 0;

  const float4* s1v = (const float4*)s1;
  size_t rb = ((size_t)ts * BB + b) * 32 + cg * 4;
  float4 c0 = s1v[rb], c1 = s1v[rb + 1], c2 = s1v[rb + 2], c3 = s1v[rb + 3];

  float v0 = 0.0f, v1 = 0.0f, v2 = 0.0f, v3 = 0.0f;

  for (int t = ts; t < t0 + 256; ++t) {
    int tn = (t + 1 < T_STEPS) ? t + 1 : t;
    size_t rn = ((size_t)tn * BB + b) * 32 + cg * 4;
    float4 n0 = s1v[rn], n1 = s1v[rn + 1], n2 = s1v[rn + 2], n3 = s1v[rn + 3];

    float a0, a1, a2, a3;
    {
      // j = 0 .. 3, each as two 8-deep chains for ILP
      float p, q;
      p = c0.x * w[0];  p = fmaf(c0.y, w[1],  p); p = fmaf(c0.z, w[2],  p); p = fmaf(c0.w, w[3],  p);
      p = fmaf(c1.x, w[4],  p); p = fmaf(c1.y, w[5],  p); p = fmaf(c1.z, w[6],  p); p = fmaf(c1.w, w[7],  p);
      q = c2.x * w[8];  q = fmaf(c2.y, w[9],  q); q = fmaf(c2.z, w[10], q); q = fmaf(c2.w, w[11], q);
      q = fmaf(c3.x, w[12], q); q = fmaf(c3.y, w[13], q); q = fmaf(c3.z, w[14], q); q = fmaf(c3.w, w[15], q);
      a0 = p + q;
      p = c0.x * w[16]; p = fmaf(c0.y, w[17], p); p = fmaf(c0.z, w[18], p); p = fmaf(c0.w, w[19], p);
      p = fmaf(c1.x, w[20], p); p = fmaf(c1.y, w[21], p); p = fmaf(c1.z, w[22], p); p = fmaf(c1.w, w[23], p);
      q = c2.x * w[24]; q = fmaf(c2.y, w[25], q); q = fmaf(c2.z, w[26], q); q = fmaf(c2.w, w[27], q);
      q = fmaf(c3.x, w[28], q); q = fmaf(c3.y, w[29], q); q = fmaf(c3.z, w[30], q); q = fmaf(c3.w, w[31], q);
      a1 = p + q;
      p = c0.x * w[32]; p = fmaf(c0.y, w[33], p); p = fmaf(c0.z, w[34], p); p = fmaf(c0.w, w[35], p);
      p = fmaf(c1.x, w[36], p); p = fmaf(c1.y, w[37], p); p = fmaf(c1.z, w[38], p); p = fmaf(c1.w, w[39], p);
      q = c2.x * w[40]; q = fmaf(c2.y, w[41], q); q = fmaf(c2.z, w[42], q); q = fmaf(c2.w, w[43], q);
      q = fmaf(c3.x, w[44], q); q = fmaf(c3.y, w[45], q); q = fmaf(c3.z, w[46], q); q = fmaf(c3.w, w[47], q);
      a2 = p + q;
      p = c0.x * w[48]; p = fmaf(c0.y, w[49], p); p = fmaf(c0.z, w[50], p); p = fmaf(c0.w, w[51], p);
      p = fmaf(c1.x, w[52], p); p = fmaf(c1.y, w[53], p); p = fmaf(c1.z, w[54], p); p = fmaf(c1.w, w[55], p);
      q = c2.x * w[56]; q = fmaf(c2.y, w[57], q); q = fmaf(c2.z, w[58], q); q = fmaf(c2.w, w[59], q);
      q = fmaf(c3.x, w[60], q); q = fmaf(c3.y, w[61], q); q = fmaf(c3.z, w[62], q); q = fmaf(c3.w, w[63], q);
      a3 = p + q;
    }

    // reduce over the 8 c-lanes (xor butterfly -> identical on all 8)
    a0 += __shfl_xor(a0, 1); a0 += __shfl_xor(a0, 2); a0 += __shfl_xor(a0, 4);
    a1 += __shfl_xor(a1, 1); a1 += __shfl_xor(a1, 2); a1 += __shfl_xor(a1, 4);
    a2 += __shfl_xor(a2, 1); a2 += __shfl_xor(a2, 2); a2 += __shfl_xor(a2, 4);
    a3 += __shfl_xor(a3, 1); a3 += __shfl_xor(a3, 2); a3 += __shfl_xor(a3, 4);

    // LIF for the 4 h's
    v0 = fmaf(v0, 0.5f, a0); bool sp0 = (v0 >= 1.0f); if (sp0) v0 = 0.0f;
    v1 = fmaf(v1, 0.5f, a1); bool sp1 = (v1 >= 1.0f); if (sp1) v1 = 0.0f;
    v2 = fmaf(v2, 0.5f, a2); bool sp2 = (v2 >= 1.0f); if (sp2) v2 = 0.0f;
    v3 = fmaf(v3, 0.5f, a3); bool sp3 = (v3 >= 1.0f); if (sp3) v3 = 0.0f;

    if (t >= t0) {                         // wave-uniform condition
      int nib = (sp0 ? 1 : 0) | (sp1 ? 2 : 0) | (sp2 ? 4 : 0) | (sp3 ? 8 : 0);
      int pn  = __shfl_xor(nib, 8);        // partner quad's nibble
      if (cg == 0 && (hq & 1) == 0) {      // lanes 0,16,32,48 -> bytes o=0..3
        int o = hq >> 1;
        s2[((size_t)t * BB + b) * 32 + hg * 16 + wv * 4 + o] =
            (unsigned char)(nib | (pn << 4));
      }
    }

    c0 = n0; c1 = n1; c2 = n2; c3 = n3;
  }
}

// ---------------- K3: u3 = s2bits @ W2^T, parallel over (t,b) ----------------
// grid 512, block 256: t = blk*4 + tid/64, b = tid%64
__global__ __launch_bounds__(256) void k3_gemm3(
    const unsigned char* __restrict__ s2, const float* __restrict__ W2,
    float* __restrict__ u3) {
  const int tid = threadIdx.x;
  const int b = tid & 63;
  const int t = blockIdx.x * 4 + (tid >> 6);

  const uint4* p = (const uint4*)(s2 + ((size_t)t * BB + b) * 32);
  uint4 q0 = p[0], q1 = p[1];
  unsigned int wd[8] = {q0.x, q0.y, q0.z, q0.w, q1.x, q1.y, q1.z, q1.w};

  float acc[NCLS];
#pragma unroll
  for (int n = 0; n < NCLS; ++n) acc[n] = 0.0f;

#pragma unroll
  for (int wi = 0; wi < 8; ++wi) {
    unsigned int u = wd[wi];
    for (int pb = 0; pb < 32; ++pb) {   // bit pb of word wi -> h = 32*wi + pb
      float f = (float)((u >> pb) & 1u);
      int h = wi * 32 + pb;
#pragma unroll
      for (int n = 0; n < NCLS; ++n)
        acc[n] = fmaf(f, W2[n * HH + h], acc[n]);  // wave-uniform -> s_load
    }
  }
#pragma unroll
  for (int n = 0; n < NCLS; ++n)
    u3[((size_t)t * NCLS + n) * BB + b] = acc[n];
}

// ---------------- K4: LIF3 + spike count, t-chunked ----------------
__global__ __launch_bounds__(64) void k4_lif3(
    const float* __restrict__ u3, float* __restrict__ out) {
  const int b  = threadIdx.x;
  const int nc = blockIdx.x;
  const int t0 = blockIdx.y * 256;

  float v = 0.0f, cnt = 0.0f;
#pragma unroll 8
  for (int t = t0 - 64; t < t0 + 256; ++t) {
    float u = 0.0f;
    if (t >= 0) u = u3[((size_t)t * NCLS + nc) * BB + b];
    v = fmaf(v, 0.5f, u);
    bool sp = (v >= 1.0f);
    if (sp && t >= t0) cnt += 1.0f;
    if (sp) v = 0.0f;
  }
  atomicAdd(&out[b * NCLS + nc], cnt * (1.0f / 2048.0f));  // exact dyadic sums
}

extern "C" void kernel_launch(void* const* d_in, const int* in_sizes, int n_in,
                              void* d_out, int out_size, void* d_ws, size_t ws_size,
                              hipStream_t stream) {
  const float* x  = (const float*)d_in[0];   // [64,2048]
  const float* cw = (const float*)d_in[1];   // [128,1,7]
  const float* W1 = (const float*)d_in[2];   // [256,128]
  const float* W2 = (const float*)d_in[3];   // [10,256]
  float* out = (float*)d_out;                // [64,10]

  char* ws = (char*)d_ws;
  float*         s1 = (float*)(ws + S1_OFF);
  unsigned char* s2 = (unsigned char*)(ws + S2_OFF);
  float*         u3 = (float*)(ws + U3_OFF);

  hipMemsetAsync(d_out, 0, 64 * NCLS * sizeof(float), stream);

  k1_conv_lif1<<<dim3(16, 64), 128, 0, stream>>>(x, cw, s1);
  k2_gemm2_lif2<<<dim3(2, 64, 8), 256, 0, stream>>>(s1, W1, s2);
  k3_gemm3<<<dim3(512), 256, 0, stream>>>(s2, W2, u3);
  k4_lif3<<<dim3(NCLS, 8), 64, 0, stream>>>(u3, out);
  (void)in_sizes; (void)n_in; (void)out_size; (void)ws_size;
}

// Round 3
// 420.216 us; speedup vs baseline: 3.8847x; 1.1348x over previous
//
#include <hip/hip_runtime.h>
#include <stdint.h>

#define T_STEPS 2048
#define BB 64
#define CC 128
#define HH 256
#define NCLS 10

// ws layout:
//   s1 fp32 [T][B][C]    : 2048*64*128*4 = 67108864 B
//   s2 bytes [T][B][32]  : 2048*64*32    =  4194304 B   (bit j of byte k -> h = 8k+j)
//   u3 fp32 [T][NC][B]   : 2048*10*64*4  =  5242880 B
#define S1_OFF 0
#define S2_OFF 67108864
#define U3_OFF 71303168

// DPP-based cross-lane add: x + x_from_lane(pattern). All VALU, no LDS pipe.
// quad_perm(1,0,3,2)=0xB1 (xor1), quad_perm(2,3,0,1)=0x4E (xor2),
// row_half_mirror=0x141 (i -> 7-i within each 8 = xor7), row_ror:8=0x128 (xor8 in row16).
#define DPP_ADD_F(x, ctrl)                                                   \
  ((x) + __int_as_float(__builtin_amdgcn_update_dpp(                         \
             0, __float_as_int(x), (ctrl), 0xF, 0xF, true)))

// ---------------- K1: conv1d(1->128,K=7,pad=3) + LIF1, t-chunked ----------------
// grid (16 chunks, 64 b), block 128 (c). chunk=128 steps, warmup=64.
__global__ __launch_bounds__(128) void k1_conv_lif1(
    const float* __restrict__ x, const float* __restrict__ cw,
    float* __restrict__ s1) {
  const int c = threadIdx.x;
  const int b = blockIdx.y;
  const int t0 = blockIdx.x * 128;
  const int ts = t0 - 64;

  float w[7];
#pragma unroll
  for (int k = 0; k < 7; ++k) w[k] = cw[c * 7 + k];

  const float* xb = x + b * 2048;
  float xw[7];
#pragma unroll
  for (int k = 0; k < 7; ++k) {
    int l = ts + k - 3;
    xw[k] = (l >= 0 && l < 2048) ? xb[l] : 0.0f;
  }

  float v = 0.0f;
#pragma unroll 7
  for (int t = ts; t < t0 + 128; ++t) {
    float u = fmaf(w[0], xw[0],
              fmaf(w[1], xw[1],
              fmaf(w[2], xw[2],
              fmaf(w[3], xw[3],
              fmaf(w[4], xw[4],
              fmaf(w[5], xw[5], w[6] * xw[6]))))));
    v = fmaf(v, 0.5f, u);             // v*0.5 exact -> fmaf == ref's mul-then-add
    bool sp = (v >= 1.0f);
    if (t >= t0) s1[((size_t)t * BB + b) * CC + c] = sp ? 1.0f : 0.0f;
    if (sp) v = 0.0f;
#pragma unroll
    for (int k = 0; k < 6; ++k) xw[k] = xw[k + 1];
    int ln = t + 4;
    xw[6] = (ln >= 0 && ln < 2048) ? xb[ln] : 0.0f;
  }
}

// ---------------- K2: fused (s1 @ W1^T) + LIF2 -> s2 bits, t-chunked -----------
// grid (2 hg, 64 b, 8 chunks), block 256 (4 waves).
// Thread = 4 h x 16 c: lane = hq*8+cg; hq=0..7 (h-quad), cg=0..7 (c-group of 16).
// h0 = hg*128 + wave*32 + hq*4.  c-chunk = cg*16.
// Chunk = 256 steps + 64-step speculative warmup (decay 0.5^64 -> exact resync;
// validated absmax 0 in R1/R2). 8-lane reduce via DPP xor1/xor2/mirror7 --
// bitwise-identical to the old xor1/xor2/xor4 butterfly (quad-sums commute),
// all lanes of a c-group end with identical sums. Nibble exchange via row_ror:8.
__global__ __launch_bounds__(256, 4) void k2_gemm2_lif2(
    const float* __restrict__ s1, const float* __restrict__ W1,
    unsigned char* __restrict__ s2) {
  const int tid  = threadIdx.x;
  const int lane = tid & 63;
  const int wv   = tid >> 6;        // 0..3
  const int cg   = lane & 7;        // 0..7  c-group
  const int hq   = lane >> 3;       // 0..7  h-quad within wave
  const int hg   = blockIdx.x;      // 0..1
  const int b    = blockIdx.y;      // 0..63
  const int t0   = blockIdx.z * 256;
  const int h0   = hg * 128 + wv * 32 + hq * 4;
  const int cb   = cg * 16;

  float w[64];
#pragma unroll
  for (int j = 0; j < 4; ++j) {
    const float4* wp = (const float4*)(W1 + (size_t)(h0 + j) * CC + cb);
#pragma unroll
    for (int k = 0; k < 4; ++k) {
      float4 f = wp[k];
      w[j * 16 + 4 * k + 0] = f.x;
      w[j * 16 + 4 * k + 1] = f.y;
      w[j * 16 + 4 * k + 2] = f.z;
      w[j * 16 + 4 * k + 3] = f.w;
    }
  }

  int ts = t0 - 64;
  if (ts < 0) ts = 0;

  // current-row pointer; advances by one t (BB*32 = 2048 float4) per step.
  // Final iteration's prefetch at t=2048 lands in the s2 region of ws --
  // valid memory, value discarded.
  const float4* p = (const float4*)s1 + ((size_t)ts * BB + b) * 32 + cg * 4;
  float4 c0 = p[0], c1 = p[1], c2 = p[2], c3 = p[3];

  float v0 = 0.0f, v1 = 0.0f, v2 = 0.0f, v3 = 0.0f;

  for (int t = ts; t < t0 + 256; ++t) {
    p += 2048;
    float4 n0 = p[0], n1 = p[1], n2 = p[2], n3 = p[3];

    float a0, a1, a2, a3;
    {
      float pp, qq;
      pp = c0.x * w[0];  pp = fmaf(c0.y, w[1],  pp); pp = fmaf(c0.z, w[2],  pp); pp = fmaf(c0.w, w[3],  pp);
      pp = fmaf(c1.x, w[4],  pp); pp = fmaf(c1.y, w[5],  pp); pp = fmaf(c1.z, w[6],  pp); pp = fmaf(c1.w, w[7],  pp);
      qq = c2.x * w[8];  qq = fmaf(c2.y, w[9],  qq); qq = fmaf(c2.z, w[10], qq); qq = fmaf(c2.w, w[11], qq);
      qq = fmaf(c3.x, w[12], qq); qq = fmaf(c3.y, w[13], qq); qq = fmaf(c3.z, w[14], qq); qq = fmaf(c3.w, w[15], qq);
      a0 = pp + qq;
      pp = c0.x * w[16]; pp = fmaf(c0.y, w[17], pp); pp = fmaf(c0.z, w[18], pp); pp = fmaf(c0.w, w[19], pp);
      pp = fmaf(c1.x, w[20], pp); pp = fmaf(c1.y, w[21], pp); pp = fmaf(c1.z, w[22], pp); pp = fmaf(c1.w, w[23], pp);
      qq = c2.x * w[24]; qq = fmaf(c2.y, w[25], qq); qq = fmaf(c2.z, w[26], qq); qq = fmaf(c2.w, w[27], qq);
      qq = fmaf(c3.x, w[28], qq); qq = fmaf(c3.y, w[29], qq); qq = fmaf(c3.z, w[30], qq); qq = fmaf(c3.w, w[31], qq);
      a1 = pp + qq;
      pp = c0.x * w[32]; pp = fmaf(c0.y, w[33], pp); pp = fmaf(c0.z, w[34], pp); pp = fmaf(c0.w, w[35], pp);
      pp = fmaf(c1.x, w[36], pp); pp = fmaf(c1.y, w[37], pp); pp = fmaf(c1.z, w[38], pp); pp = fmaf(c1.w, w[39], pp);
      qq = c2.x * w[40]; qq = fmaf(c2.y, w[41], qq); qq = fmaf(c2.z, w[42], qq); qq = fmaf(c2.w, w[43], qq);
      qq = fmaf(c3.x, w[44], qq); qq = fmaf(c3.y, w[45], qq); qq = fmaf(c3.z, w[46], qq); qq = fmaf(c3.w, w[47], qq);
      a2 = pp + qq;
      pp = c0.x * w[48]; pp = fmaf(c0.y, w[49], pp); pp = fmaf(c0.z, w[50], pp); pp = fmaf(c0.w, w[51], pp);
      pp = fmaf(c1.x, w[52], pp); pp = fmaf(c1.y, w[53], pp); pp = fmaf(c1.z, w[54], pp); pp = fmaf(c1.w, w[55], pp);
      qq = c2.x * w[56]; qq = fmaf(c2.y, w[57], qq); qq = fmaf(c2.z, w[58], qq); qq = fmaf(c2.w, w[59], qq);
      qq = fmaf(c3.x, w[60], qq); qq = fmaf(c3.y, w[61], qq); qq = fmaf(c3.z, w[62], qq); qq = fmaf(c3.w, w[63], qq);
      a3 = pp + qq;
    }

    // 8-lane reduce, all-DPP: xor1, xor2, mirror(=xor7). All 8 c-lanes identical.
    a0 = DPP_ADD_F(a0, 0xB1); a0 = DPP_ADD_F(a0, 0x4E); a0 = DPP_ADD_F(a0, 0x141);
    a1 = DPP_ADD_F(a1, 0xB1); a1 = DPP_ADD_F(a1, 0x4E); a1 = DPP_ADD_F(a1, 0x141);
    a2 = DPP_ADD_F(a2, 0xB1); a2 = DPP_ADD_F(a2, 0x4E); a2 = DPP_ADD_F(a2, 0x141);
    a3 = DPP_ADD_F(a3, 0xB1); a3 = DPP_ADD_F(a3, 0x4E); a3 = DPP_ADD_F(a3, 0x141);

    // LIF for the 4 h's
    v0 = fmaf(v0, 0.5f, a0); bool sp0 = (v0 >= 1.0f); if (sp0) v0 = 0.0f;
    v1 = fmaf(v1, 0.5f, a1); bool sp1 = (v1 >= 1.0f); if (sp1) v1 = 0.0f;
    v2 = fmaf(v2, 0.5f, a2); bool sp2 = (v2 >= 1.0f); if (sp2) v2 = 0.0f;
    v3 = fmaf(v3, 0.5f, a3); bool sp3 = (v3 >= 1.0f); if (sp3) v3 = 0.0f;

    if (t >= t0) {                         // wave-uniform condition
      int nib = (sp0 ? 1 : 0) | (sp1 ? 2 : 0) | (sp2 ? 4 : 0) | (sp3 ? 8 : 0);
      int pn  = __builtin_amdgcn_update_dpp(0, nib, 0x128, 0xF, 0xF, true); // xor8
      if (cg == 0 && (hq & 1) == 0) {      // lanes 0,16,32,48 -> bytes o=0..3
        int o = hq >> 1;
        s2[((size_t)t * BB + b) * 32 + hg * 16 + wv * 4 + o] =
            (unsigned char)(nib | (pn << 4));
      }
    }

    c0 = n0; c1 = n1; c2 = n2; c3 = n3;
  }
}

// ---------------- K3: u3 = s2bits @ W2^T, parallel over (t,b) ----------------
// grid 512, block 256: t = blk*4 + tid/64, b = tid%64
__global__ __launch_bounds__(256) void k3_gemm3(
    const unsigned char* __restrict__ s2, const float* __restrict__ W2,
    float* __restrict__ u3) {
  const int tid = threadIdx.x;
  const int b = tid & 63;
  const int t = blockIdx.x * 4 + (tid >> 6);

  const uint4* p = (const uint4*)(s2 + ((size_t)t * BB + b) * 32);
  uint4 q0 = p[0], q1 = p[1];
  unsigned int wd[8] = {q0.x, q0.y, q0.z, q0.w, q1.x, q1.y, q1.z, q1.w};

  float acc[NCLS];
#pragma unroll
  for (int n = 0; n < NCLS; ++n) acc[n] = 0.0f;

#pragma unroll
  for (int wi = 0; wi < 8; ++wi) {
    unsigned int u = wd[wi];
    for (int pb = 0; pb < 32; ++pb) {   // bit pb of word wi -> h = 32*wi + pb
      float f = (float)((u >> pb) & 1u);
      int h = wi * 32 + pb;
#pragma unroll
      for (int n = 0; n < NCLS; ++n)
        acc[n] = fmaf(f, W2[n * HH + h], acc[n]);  // wave-uniform -> s_load
    }
  }
#pragma unroll
  for (int n = 0; n < NCLS; ++n)
    u3[((size_t)t * NCLS + n) * BB + b] = acc[n];
}

// ---------------- K4: LIF3 + spike count, t-chunked ----------------
// grid (10 nc, 32 chunks), block 64 (b). chunk=64 steps, warmup=64 (exact).
__global__ __launch_bounds__(64) void k4_lif3(
    const float* __restrict__ u3, float* __restrict__ out) {
  const int b  = threadIdx.x;
  const int nc = blockIdx.x;
  const int t0 = blockIdx.y * 64;

  float v = 0.0f, cnt = 0.0f;
#pragma unroll 8
  for (int t = t0 - 64; t < t0 + 64; ++t) {
    float u = 0.0f;
    if (t >= 0) u = u3[((size_t)t * NCLS + nc) * BB + b];
    v = fmaf(v, 0.5f, u);
    bool sp = (v >= 1.0f);
    if (sp && t >= t0) cnt += 1.0f;
    if (sp) v = 0.0f;
  }
  atomicAdd(&out[b * NCLS + nc], cnt * (1.0f / 2048.0f));  // exact dyadic sums
}

extern "C" void kernel_launch(void* const* d_in, const int* in_sizes, int n_in,
                              void* d_out, int out_size, void* d_ws, size_t ws_size,
                              hipStream_t stream) {
  const float* x  = (const float*)d_in[0];   // [64,2048]
  const float* cw = (const float*)d_in[1];   // [128,1,7]
  const float* W1 = (const float*)d_in[2];   // [256,128]
  const float* W2 = (const float*)d_in[3];   // [10,256]
  float* out = (float*)d_out;                // [64,10]

  char* ws = (char*)d_ws;
  float*         s1 = (float*)(ws + S1_OFF);
  unsigned char* s2 = (unsigned char*)(ws + S2_OFF);
  float*         u3 = (float*)(ws + U3_OFF);

  hipMemsetAsync(d_out, 0, 64 * NCLS * sizeof(float), stream);

  k1_conv_lif1<<<dim3(16, 64), 128, 0, stream>>>(x, cw, s1);
  k2_gemm2_lif2<<<dim3(2, 64, 8), 256, 0, stream>>>(s1, W1, s2);
  k3_gemm3<<<dim3(512), 256, 0, stream>>>(s2, W2, u3);
  k4_lif3<<<dim3(NCLS, 32), 64, 0, stream>>>(u3, out);
  (void)in_sizes; (void)n_in; (void)out_size; (void)ws_size;
}

// Round 4
// 368.426 us; speedup vs baseline: 4.4308x; 1.1406x over previous
//
#include <hip/hip_runtime.h>
#include <stdint.h>

#define T_STEPS 2048
#define BB 64
#define CC 128
#define HH 256
#define NCLS 10

// ws layout:
//   s1 bytes [T][B][C]   : 2048*64*128   = 16777216 B  (0/1 spikes)
//   s2 bytes [T][B][32]  : 2048*64*32    =  4194304 B  (bit j of byte k -> h = 8k+j)
//   u3 fp32 [T][NC][B]   : 2048*10*64*4  =  5242880 B
#define S1_OFF 0
#define S2_OFF 16777216
#define U3_OFF 20971520

// DPP cross-lane add: x + x_from_lane(pattern). All VALU, no LDS pipe.
// 0xB1 quad_perm(1,0,3,2)=xor1, 0x4E quad_perm(2,3,0,1)=xor2,
// 0x141 row_half_mirror (xor7 within 8), 0x128 row_ror:8 (xor8 within row16).
#define DPP_ADD_F(x, ctrl)                                                   \
  ((x) + __int_as_float(__builtin_amdgcn_update_dpp(                         \
             0, __float_as_int(x), (ctrl), 0xF, 0xF, true)))

// ---------------- K1: conv1d(1->128,K=7,pad=3) + LIF1 -> s1 bytes --------------
// grid (16 chunks, 64 b), block 128 (c). chunk=128 steps, warmup=64 (exact:
// decay 0.5^64 underflows; any common spike hard-resets v to 0).
__global__ __launch_bounds__(128) void k1_conv_lif1(
    const float* __restrict__ x, const float* __restrict__ cw,
    unsigned char* __restrict__ s1) {
  const int c = threadIdx.x;
  const int b = blockIdx.y;
  const int t0 = blockIdx.x * 128;
  const int ts = t0 - 64;

  float w[7];
#pragma unroll
  for (int k = 0; k < 7; ++k) w[k] = cw[c * 7 + k];

  const float* xb = x + b * 2048;
  float xw[7];
#pragma unroll
  for (int k = 0; k < 7; ++k) {
    int l = ts + k - 3;
    xw[k] = (l >= 0 && l < 2048) ? xb[l] : 0.0f;
  }

  float v = 0.0f;
#pragma unroll 7
  for (int t = ts; t < t0 + 128; ++t) {
    float u = fmaf(w[0], xw[0],
              fmaf(w[1], xw[1],
              fmaf(w[2], xw[2],
              fmaf(w[3], xw[3],
              fmaf(w[4], xw[4],
              fmaf(w[5], xw[5], w[6] * xw[6]))))));
    v = fmaf(v, 0.5f, u);             // v*0.5 exact -> fmaf == ref's mul-then-add
    bool sp = (v >= 1.0f);
    if (t >= t0) s1[((size_t)t * BB + b) * CC + c] = (unsigned char)(sp ? 1 : 0);
    if (sp) v = 0.0f;
#pragma unroll
    for (int k = 0; k < 6; ++k) xw[k] = xw[k + 1];
    int ln = t + 4;
    xw[6] = (ln >= 0 && ln < 2048) ? xb[ln] : 0.0f;
  }
}

// ---------------- K2: fused (s1 @ W1^T) + LIF2 -> s2 bits, t-chunked -----------
// grid (2 hg, 64 b, 8 chunks), block 256 (4 waves).
// Thread = 4 h x 16 c: lane = hq*8+cg; hq=0..7 (h-quad), cg=0..7 (c-group of 16).
// h0 = hg*128 + wave*32 + hq*4.  c bytes at cb = cg*16 -> one dwordx4 per step,
// decoded with v_cvt_f32_ubyte (spikes are exactly 0.0/1.0 -> fp32 math
// identical to the R2/R3 kernels, absmax 0). 2-deep prefetch: load for t+2
// issued at t (window ~1900 cyc >> 900 cyc HBM latency). Final prefetches
// overrun into the s2 region of ws -- valid memory, values discarded.
// 8-lane DPP butterfly (xor1/xor2/mirror7) -> all 8 c-lanes identical sums.
__global__ __launch_bounds__(256, 4) void k2_gemm2_lif2(
    const unsigned char* __restrict__ s1, const float* __restrict__ W1,
    unsigned char* __restrict__ s2) {
  const int tid  = threadIdx.x;
  const int lane = tid & 63;
  const int wv   = tid >> 6;        // 0..3
  const int cg   = lane & 7;        // 0..7  c-group
  const int hq   = lane >> 3;       // 0..7  h-quad within wave
  const int hg   = blockIdx.x;      // 0..1
  const int b    = blockIdx.y;      // 0..63
  const int t0   = blockIdx.z * 256;
  const int h0   = hg * 128 + wv * 32 + hq * 4;
  const int cb   = cg * 16;

  float w[64];
#pragma unroll
  for (int j = 0; j < 4; ++j) {
    const float4* wp = (const float4*)(W1 + (size_t)(h0 + j) * CC + cb);
#pragma unroll
    for (int k = 0; k < 4; ++k) {
      float4 f = wp[k];
      w[j * 16 + 4 * k + 0] = f.x;
      w[j * 16 + 4 * k + 1] = f.y;
      w[j * 16 + 4 * k + 2] = f.z;
      w[j * 16 + 4 * k + 3] = f.w;
    }
  }

  int ts = t0 - 64;
  if (ts < 0) ts = 0;

  // uint4 view: one t-row = 128 B = 8 uint4; t-stride = 64 rows = 512 uint4.
  const uint4* pb = (const uint4*)s1 + ((size_t)ts * BB + b) * 8 + cg;
  uint4 qa = pb[0];          // t = ts
  uint4 qb = pb[512];        // t = ts+1
  pb += 1024;                // points at t = ts+2

  float v0 = 0.0f, v1 = 0.0f, v2 = 0.0f, v3 = 0.0f;

#pragma unroll 2
  for (int t = ts; t < t0 + 256; ++t) {
    uint4 cur = qa;
    qa = qb;
    qb = pb[0];              // prefetch t+2
    pb += 512;

    // decode 16 spike bytes -> exact 0.0f/1.0f
    float xv[16];
    {
      unsigned int wd[4] = {cur.x, cur.y, cur.z, cur.w};
#pragma unroll
      for (int k = 0; k < 4; ++k) {
        unsigned int u = wd[k];
        xv[4 * k + 0] = (float)(u & 0xffu);
        xv[4 * k + 1] = (float)((u >> 8) & 0xffu);
        xv[4 * k + 2] = (float)((u >> 16) & 0xffu);
        xv[4 * k + 3] = (float)(u >> 24);
      }
    }

    float a[4];
#pragma unroll
    for (int j = 0; j < 4; ++j) {
      float s = xv[0] * w[16 * j];
#pragma unroll
      for (int k = 1; k < 16; ++k) s = fmaf(xv[k], w[16 * j + k], s);
      a[j] = s;
    }

    // 8-lane reduce, all-DPP: xor1, xor2, mirror(=xor7). All 8 c-lanes identical.
#pragma unroll
    for (int j = 0; j < 4; ++j) {
      a[j] = DPP_ADD_F(a[j], 0xB1);
      a[j] = DPP_ADD_F(a[j], 0x4E);
      a[j] = DPP_ADD_F(a[j], 0x141);
    }

    // LIF for the 4 h's
    v0 = fmaf(v0, 0.5f, a[0]); bool sp0 = (v0 >= 1.0f); if (sp0) v0 = 0.0f;
    v1 = fmaf(v1, 0.5f, a[1]); bool sp1 = (v1 >= 1.0f); if (sp1) v1 = 0.0f;
    v2 = fmaf(v2, 0.5f, a[2]); bool sp2 = (v2 >= 1.0f); if (sp2) v2 = 0.0f;
    v3 = fmaf(v3, 0.5f, a[3]); bool sp3 = (v3 >= 1.0f); if (sp3) v3 = 0.0f;

    if (t >= t0) {                         // wave-uniform condition
      int nib = (sp0 ? 1 : 0) | (sp1 ? 2 : 0) | (sp2 ? 4 : 0) | (sp3 ? 8 : 0);
      int pn  = __builtin_amdgcn_update_dpp(0, nib, 0x128, 0xF, 0xF, true); // xor8
      if (cg == 0 && (hq & 1) == 0) {      // lanes 0,16,32,48 -> bytes o=0..3
        int o = hq >> 1;
        s2[((size_t)t * BB + b) * 32 + hg * 16 + wv * 4 + o] =
            (unsigned char)(nib | (pn << 4));
      }
    }
  }
}

// ---------------- K3: u3 = s2bits @ W2^T, parallel over (t,b) ----------------
// grid 2048 (t), block 64 (b): 8 blocks/CU for latency hiding.
__global__ __launch_bounds__(64) void k3_gemm3(
    const unsigned char* __restrict__ s2, const float* __restrict__ W2,
    float* __restrict__ u3) {
  const int b = threadIdx.x;
  const int t = blockIdx.x;

  const uint4* p = (const uint4*)(s2 + ((size_t)t * BB + b) * 32);
  uint4 q0 = p[0], q1 = p[1];
  unsigned int wd[8] = {q0.x, q0.y, q0.z, q0.w, q1.x, q1.y, q1.z, q1.w};

  float acc[NCLS];
#pragma unroll
  for (int n = 0; n < NCLS; ++n) acc[n] = 0.0f;

#pragma unroll
  for (int wi = 0; wi < 8; ++wi) {
    unsigned int u = wd[wi];
    for (int pb = 0; pb < 32; ++pb) {   // bit pb of word wi -> h = 32*wi + pb
      float f = (float)((u >> pb) & 1u);
      int h = wi * 32 + pb;
#pragma unroll
      for (int n = 0; n < NCLS; ++n)
        acc[n] = fmaf(f, W2[n * HH + h], acc[n]);  // wave-uniform -> s_load
    }
  }
#pragma unroll
  for (int n = 0; n < NCLS; ++n)
    u3[((size_t)t * NCLS + n) * BB + b] = acc[n];
}

// ---------------- K4: LIF3 + spike count, t-chunked ----------------
// grid (10 nc, 32 chunks), block 64 (b). chunk=64 steps, warmup=64 (exact).
__global__ __launch_bounds__(64) void k4_lif3(
    const float* __restrict__ u3, float* __restrict__ out) {
  const int b  = threadIdx.x;
  const int nc = blockIdx.x;
  const int t0 = blockIdx.y * 64;

  float v = 0.0f, cnt = 0.0f;
#pragma unroll 8
  for (int t = t0 - 64; t < t0 + 64; ++t) {
    float u = 0.0f;
    if (t >= 0) u = u3[((size_t)t * NCLS + nc) * BB + b];
    v = fmaf(v, 0.5f, u);
    bool sp = (v >= 1.0f);
    if (sp && t >= t0) cnt += 1.0f;
    if (sp) v = 0.0f;
  }
  atomicAdd(&out[b * NCLS + nc], cnt * (1.0f / 2048.0f));  // exact dyadic sums
}

extern "C" void kernel_launch(void* const* d_in, const int* in_sizes, int n_in,
                              void* d_out, int out_size, void* d_ws, size_t ws_size,
                              hipStream_t stream) {
  const float* x  = (const float*)d_in[0];   // [64,2048]
  const float* cw = (const float*)d_in[1];   // [128,1,7]
  const float* W1 = (const float*)d_in[2];   // [256,128]
  const float* W2 = (const float*)d_in[3];   // [10,256]
  float* out = (float*)d_out;                // [64,10]

  char* ws = (char*)d_ws;
  unsigned char* s1 = (unsigned char*)(ws + S1_OFF);
  unsigned char* s2 = (unsigned char*)(ws + S2_OFF);
  float*         u3 = (float*)(ws + U3_OFF);

  hipMemsetAsync(d_out, 0, 64 * NCLS * sizeof(float), stream);

  k1_conv_lif1<<<dim3(16, 64), 128, 0, stream>>>(x, cw, s1);
  k2_gemm2_lif2<<<dim3(2, 64, 8), 256, 0, stream>>>(s1, W1, s2);
  k3_gemm3<<<dim3(2048), 64, 0, stream>>>(s2, W2, u3);
  k4_lif3<<<dim3(NCLS, 32), 64, 0, stream>>>(u3, out);
  (void)in_sizes; (void)n_in; (void)out_size; (void)ws_size;
}

// Round 5
// 186.541 us; speedup vs baseline: 8.7510x; 1.9750x over previous
//
#include <hip/hip_runtime.h>
#include <stdint.h>

#define T_STEPS 2048
#define BB 64
#define CC 128
#define HH 256
#define NCLS 10

// ws layout:
//   s1 bytes [T][B][C]        : 2048*64*128 = 16777216 B  (0/1 spikes, i8-ready)
//   dp i8   [4][H][C]         : 4*256*128   =   131072 B  (W1 digit planes)
//   s2 bytes [T][B][32]       : 2048*64*32  =  4194304 B  (bit j of byte k -> h=8k+j)
//   u3 fp32 [T][NC][B]        : 2048*10*64*4=  5242880 B
#define S1_OFF 0
#define DP_OFF 16777216
#define S2_OFF 16908288
#define U3_OFF 21102592

typedef int v4i __attribute__((ext_vector_type(4)));

// ---------------- K0: W1 -> 4 signed base-256 digit planes ----------------
// q = rn(w * 2^31)  (|w| < 1), digits d0..d3 in [-128,127], exact:
// q = d0 + 256*(d1 + 256*(d2 + 256*d3)).
__global__ __launch_bounds__(128) void k0_digits(
    const float* __restrict__ W1, signed char* __restrict__ dp) {
  const int h = blockIdx.x;      // 0..255
  const int c = threadIdx.x;     // 0..127
  float w = W1[h * CC + c];
  int q = __float2int_rn(w * 2147483648.0f);
#pragma unroll
  for (int d = 0; d < 3; ++d) {
    int dig = (int)(signed char)(q & 0xff);
    dp[d * (HH * CC) + h * CC + c] = (signed char)dig;
    q = (q - dig) >> 8;
  }
  dp[3 * (HH * CC) + h * CC + c] = (signed char)q;
}

// ---------------- K1: conv1d(1->128,K=7,pad=3) + LIF1 -> s1 bytes --------------
// grid (16 chunks, 64 b), block 128 (c). chunk=128 steps, warmup=64 (exact:
// decay 0.5^64 underflows; any common spike hard-resets v to 0).
__global__ __launch_bounds__(128) void k1_conv_lif1(
    const float* __restrict__ x, const float* __restrict__ cw,
    unsigned char* __restrict__ s1) {
  const int c = threadIdx.x;
  const int b = blockIdx.y;
  const int t0 = blockIdx.x * 128;
  const int ts = t0 - 64;

  float w[7];
#pragma unroll
  for (int k = 0; k < 7; ++k) w[k] = cw[c * 7 + k];

  const float* xb = x + b * 2048;
  float xw[7];
#pragma unroll
  for (int k = 0; k < 7; ++k) {
    int l = ts + k - 3;
    xw[k] = (l >= 0 && l < 2048) ? xb[l] : 0.0f;
  }

  float v = 0.0f;
#pragma unroll 7
  for (int t = ts; t < t0 + 128; ++t) {
    float u = fmaf(w[0], xw[0],
              fmaf(w[1], xw[1],
              fmaf(w[2], xw[2],
              fmaf(w[3], xw[3],
              fmaf(w[4], xw[4],
              fmaf(w[5], xw[5], w[6] * xw[6]))))));
    v = fmaf(v, 0.5f, u);             // v*0.5 exact -> fmaf == ref's mul-then-add
    bool sp = (v >= 1.0f);
    if (t >= t0) s1[((size_t)t * BB + b) * CC + c] = (unsigned char)(sp ? 1 : 0);
    if (sp) v = 0.0f;
#pragma unroll
    for (int k = 0; k < 6; ++k) xw[k] = xw[k + 1];
    int ln = t + 4;
    xw[6] = (ln >= 0 && ln < 2048) ? xb[ln] : 0.0f;
  }
}

// ---------------- K2: fused MFMA-i8 (s1 @ W1^T) + LIF2 -> s2 bits --------------
// grid (2 hg, 64 b, 8 chunks), block 256 (4 waves), t-chunk = 256 steps
// (+64-step warmup for chunk>0; chunk 0 starts exactly at v=0).
// Per sub-chunk of 16 t: each wave does A = s1 16t x 128c (i8, direct bytes),
// B = digit planes for its 32 h (preloaded, 64 VGPRs), 16 x mfma_i32_16x16x64_i8
// (2 N-tiles x 2 K-chunks x 4 digits; integer-exact). Digit recombine gives
// fl(exact subset-sum of quantized weights) -- one fp32 rounding, quantization
// <= 128*2^-32 ~ 3e-8, below the reorder noise that has passed 4 rounds.
// u2 goes through LDS [128h][17t] (2-way bank aliasing = free), never HBM.
// Threads 0..127 scan LIF over the 16 steps, ballot -> s2 bits.
__global__ __launch_bounds__(256, 4) void k2_mfma_lif2(
    const unsigned char* __restrict__ s1, const signed char* __restrict__ dp,
    unsigned char* __restrict__ s2) {
  const int tid  = threadIdx.x;
  const int lane = tid & 63;
  const int wv   = tid >> 6;        // 0..3
  const int hg   = blockIdx.x;      // 0..1
  const int b    = blockIdx.y;      // 0..63
  const int chunk= blockIdx.z;      // 0..7
  const int t0   = chunk * 256;
  const int nwarm= (chunk == 0) ? 0 : 4;      // warmup sub-chunks (x16 t)
  const int ts   = t0 - nwarm * 16;
  const int l15  = lane & 15;
  const int lg   = lane >> 4;       // 0..3 (k-group)

  // B fragments: wave's 32 h = hg*128 + wv*32 + n*16 + (lane&15), n=0,1.
  // B[k][n]: lane holds k = kc*64 + lg*16 + j, j=0..15 -> 16 consecutive c bytes.
  v4i Bf[2][4][2];
#pragma unroll
  for (int n = 0; n < 2; ++n) {
    const int h = hg * 128 + wv * 32 + n * 16 + l15;
#pragma unroll
    for (int d = 0; d < 4; ++d)
#pragma unroll
      for (int kc = 0; kc < 2; ++kc)
        Bf[n][d][kc] = *(const v4i*)(dp + d * (HH * CC) + h * CC + kc * 64 + lg * 16);
  }

  __shared__ float smem[128 * 17];

  // A row pointer: lane reads s1 row m = tb + (lane&15), bytes kc*64 + lg*16.
  const unsigned char* ap =
      s1 + ((size_t)(ts + l15) * BB + b) * CC + lg * 16;

  float v = 0.0f;   // LIF2 state for threads 0..127 (h = hg*128 + tid)

  const int nsub = nwarm + 16;
  for (int s = 0; s < nsub; ++s) {
    const int tb = ts + s * 16;

    v4i Af0 = *(const v4i*)(ap);
    v4i Af1 = *(const v4i*)(ap + 64);
    ap += 16 * BB * CC;

#pragma unroll
    for (int n = 0; n < 2; ++n) {
      v4i a0 = {0, 0, 0, 0}, a1 = {0, 0, 0, 0}, a2 = {0, 0, 0, 0}, a3 = {0, 0, 0, 0};
      a0 = __builtin_amdgcn_mfma_i32_16x16x64_i8(Af0, Bf[n][0][0], a0, 0, 0, 0);
      a1 = __builtin_amdgcn_mfma_i32_16x16x64_i8(Af0, Bf[n][1][0], a1, 0, 0, 0);
      a2 = __builtin_amdgcn_mfma_i32_16x16x64_i8(Af0, Bf[n][2][0], a2, 0, 0, 0);
      a3 = __builtin_amdgcn_mfma_i32_16x16x64_i8(Af0, Bf[n][3][0], a3, 0, 0, 0);
      a0 = __builtin_amdgcn_mfma_i32_16x16x64_i8(Af1, Bf[n][0][1], a0, 0, 0, 0);
      a1 = __builtin_amdgcn_mfma_i32_16x16x64_i8(Af1, Bf[n][1][1], a1, 0, 0, 0);
      a2 = __builtin_amdgcn_mfma_i32_16x16x64_i8(Af1, Bf[n][2][1], a2, 0, 0, 0);
      a3 = __builtin_amdgcn_mfma_i32_16x16x64_i8(Af1, Bf[n][3][1], a3, 0, 0, 0);

      // recombine digits -> fp32, write LDS. C-layout: col=lane&15, row=lg*4+r.
      const int hl = wv * 32 + n * 16 + l15;      // 0..127 within block
#pragma unroll
      for (int r = 0; r < 4; ++r) {
        int hi = a3[r] * 256 + a2[r];             // exact, |.| < 2^22
        int lo = a1[r] * 256 + a0[r];
        float u = fmaf((float)hi, 0x1p-15f, (float)lo * 0x1p-31f);
        smem[hl * 17 + (lg * 4 + r)] = u;
      }
    }
    __syncthreads();

    if (tid < 128) {                 // waves 0,1 scan; h = hg*128 + tid
      bool commit = (s >= nwarm);    // wave-uniform
#pragma unroll
      for (int tl = 0; tl < 16; ++tl) {
        float u = smem[tid * 17 + tl];
        v = fmaf(v, 0.5f, u);
        bool sp = (v >= 1.0f);
        if (sp) v = 0.0f;
        unsigned long long m = __ballot(sp);
        if (commit && lane == 0) {
          int t = tb + tl;
          *(uint2*)(s2 + ((size_t)t * BB + b) * 32 + hg * 16 + (tid >> 6) * 8) =
              make_uint2((unsigned int)m, (unsigned int)(m >> 32));
        }
      }
    }
    __syncthreads();
  }
}

// ---------------- K3: u3 = s2bits @ W2^T, parallel over (t,b) ----------------
// grid 2048 (t), block 64 (b): 8 blocks/CU for latency hiding.
__global__ __launch_bounds__(64) void k3_gemm3(
    const unsigned char* __restrict__ s2, const float* __restrict__ W2,
    float* __restrict__ u3) {
  const int b = threadIdx.x;
  const int t = blockIdx.x;

  const uint4* p = (const uint4*)(s2 + ((size_t)t * BB + b) * 32);
  uint4 q0 = p[0], q1 = p[1];
  unsigned int wd[8] = {q0.x, q0.y, q0.z, q0.w, q1.x, q1.y, q1.z, q1.w};

  float acc[NCLS];
#pragma unroll
  for (int n = 0; n < NCLS; ++n) acc[n] = 0.0f;

#pragma unroll
  for (int wi = 0; wi < 8; ++wi) {
    unsigned int u = wd[wi];
    for (int pb = 0; pb < 32; ++pb) {   // bit pb of word wi -> h = 32*wi + pb
      float f = (float)((u >> pb) & 1u);
      int h = wi * 32 + pb;
#pragma unroll
      for (int n = 0; n < NCLS; ++n)
        acc[n] = fmaf(f, W2[n * HH + h], acc[n]);  // wave-uniform -> s_load
    }
  }
#pragma unroll
  for (int n = 0; n < NCLS; ++n)
    u3[((size_t)t * NCLS + n) * BB + b] = acc[n];
}

// ---------------- K4: LIF3 + spike count, t-chunked ----------------
// grid (10 nc, 32 chunks), block 64 (b). chunk=64 steps, warmup=64 (exact).
__global__ __launch_bounds__(64) void k4_lif3(
    const float* __restrict__ u3, float* __restrict__ out) {
  const int b  = threadIdx.x;
  const int nc = blockIdx.x;
  const int t0 = blockIdx.y * 64;

  float v = 0.0f, cnt = 0.0f;
#pragma unroll 8
  for (int t = t0 - 64; t < t0 + 64; ++t) {
    float u = 0.0f;
    if (t >= 0) u = u3[((size_t)t * NCLS + nc) * BB + b];
    v = fmaf(v, 0.5f, u);
    bool sp = (v >= 1.0f);
    if (sp && t >= t0) cnt += 1.0f;
    if (sp) v = 0.0f;
  }
  atomicAdd(&out[b * NCLS + nc], cnt * (1.0f / 2048.0f));  // exact dyadic sums
}

extern "C" void kernel_launch(void* const* d_in, const int* in_sizes, int n_in,
                              void* d_out, int out_size, void* d_ws, size_t ws_size,
                              hipStream_t stream) {
  const float* x  = (const float*)d_in[0];   // [64,2048]
  const float* cw = (const float*)d_in[1];   // [128,1,7]
  const float* W1 = (const float*)d_in[2];   // [256,128]
  const float* W2 = (const float*)d_in[3];   // [10,256]
  float* out = (float*)d_out;                // [64,10]

  char* ws = (char*)d_ws;
  unsigned char* s1 = (unsigned char*)(ws + S1_OFF);
  signed char*   dp = (signed char*)(ws + DP_OFF);
  unsigned char* s2 = (unsigned char*)(ws + S2_OFF);
  float*         u3 = (float*)(ws + U3_OFF);

  hipMemsetAsync(d_out, 0, 64 * NCLS * sizeof(float), stream);

  k0_digits<<<dim3(HH), 128, 0, stream>>>(W1, dp);
  k1_conv_lif1<<<dim3(16, 64), 128, 0, stream>>>(x, cw, s1);
  k2_mfma_lif2<<<dim3(2, 64, 8), 256, 0, stream>>>(s1, dp, s2);
  k3_gemm3<<<dim3(2048), 64, 0, stream>>>(s2, W2, u3);
  k4_lif3<<<dim3(NCLS, 32), 64, 0, stream>>>(u3, out);
  (void)in_sizes; (void)n_in; (void)out_size; (void)ws_size;
}

// Round 6
// 149.615 us; speedup vs baseline: 10.9109x; 1.2468x over previous
//
#include <hip/hip_runtime.h>
#include <stdint.h>

#define T_STEPS 2048
#define BB 64
#define CC 128
#define HH 256
#define NCLS 10

// ws layout:
//   s1  bytes [T][B][C]     : 2048*64*128 = 16777216 B  (0/1 spikes, i8 A-operand)
//   dp  i8   [4][H][C]      : 4*256*128   =   131072 B  (W1 digit planes)
//   dp2 i8   [4][16][256]   : 4*16*256    =    16384 B  (W2 digit planes, nc padded to 16 w/ zeros)
//   s2b bytes [T][B][256]   : 2048*64*256 = 33554432 B  (0/1 spikes layer 2, i8 A-operand)
// total ~50.5 MB (+ prefetch overrun slack); prior rounds used 76.5 MB of ws OK.
#define S1_OFF  0
#define DP_OFF  16777216
#define DP2_OFF 16908288
#define S2B_OFF 16924672

typedef int v4i __attribute__((ext_vector_type(4)));

// ---------------- K0: W1/W2 -> signed base-256 digit planes ----------------
// q = rn(w * 2^31) (|w| < 1), digits d0..d3 in [-128,127], exact:
// q = d0 + 256*(d1 + 256*(d2 + 256*d3)).  Blocks 0..255: W1 row h.
// Blocks 256..271: W2 row nc (2 c-halves), rows nc>=10 zeroed.
__global__ __launch_bounds__(128) void k0_digits(
    const float* __restrict__ W1, const float* __restrict__ W2,
    signed char* __restrict__ dp, signed char* __restrict__ dp2) {
  const int blk = blockIdx.x;
  const int c = threadIdx.x;
  if (blk < HH) {
    float w = W1[blk * CC + c];
    int q = __float2int_rn(w * 2147483648.0f);
#pragma unroll
    for (int d = 0; d < 3; ++d) {
      int dig = (int)(signed char)(q & 0xff);
      dp[d * (HH * CC) + blk * CC + c] = (signed char)dig;
      q = (q - dig) >> 8;
    }
    dp[3 * (HH * CC) + blk * CC + c] = (signed char)q;
  } else {
    const int nc = blk - HH;        // 0..15
#pragma unroll
    for (int half = 0; half < 2; ++half) {
      int cc = half * 128 + c;
      float w = (nc < NCLS) ? W2[nc * HH + cc] : 0.0f;
      int q = __float2int_rn(w * 2147483648.0f);
#pragma unroll
      for (int d = 0; d < 3; ++d) {
        int dig = (int)(signed char)(q & 0xff);
        dp2[d * (16 * HH) + nc * HH + cc] = (signed char)dig;
        q = (q - dig) >> 8;
      }
      dp2[3 * (16 * HH) + nc * HH + cc] = (signed char)q;
    }
  }
}

// ---------------- K1: conv1d(1->128,K=7,pad=3) + LIF1 -> s1 bytes --------------
// grid (16 chunks, 64 b), block 128 (c). chunk=128 steps, warmup=64 (exact:
// decay 0.5^64 underflows; any common spike hard-resets v to 0).
__global__ __launch_bounds__(128) void k1_conv_lif1(
    const float* __restrict__ x, const float* __restrict__ cw,
    unsigned char* __restrict__ s1) {
  const int c = threadIdx.x;
  const int b = blockIdx.y;
  const int t0 = blockIdx.x * 128;
  const int ts = t0 - 64;

  float w[7];
#pragma unroll
  for (int k = 0; k < 7; ++k) w[k] = cw[c * 7 + k];

  const float* xb = x + b * 2048;
  float xw[7];
#pragma unroll
  for (int k = 0; k < 7; ++k) {
    int l = ts + k - 3;
    xw[k] = (l >= 0 && l < 2048) ? xb[l] : 0.0f;
  }

  float v = 0.0f;
#pragma unroll 7
  for (int t = ts; t < t0 + 128; ++t) {
    float u = fmaf(w[0], xw[0],
              fmaf(w[1], xw[1],
              fmaf(w[2], xw[2],
              fmaf(w[3], xw[3],
              fmaf(w[4], xw[4],
              fmaf(w[5], xw[5], w[6] * xw[6]))))));
    v = fmaf(v, 0.5f, u);             // v*0.5 exact -> fmaf == ref's mul-then-add
    bool sp = (v >= 1.0f);
    if (t >= t0) s1[((size_t)t * BB + b) * CC + c] = (unsigned char)(sp ? 1 : 0);
    if (sp) v = 0.0f;
#pragma unroll
    for (int k = 0; k < 6; ++k) xw[k] = xw[k + 1];
    int ln = t + 4;
    xw[6] = (ln >= 0 && ln < 2048) ? xb[ln] : 0.0f;
  }
}

// ---------------- K2: fused MFMA-i8 (s1 @ W1^T) + LIF2 -> s2 bytes -------------
// grid (2 hg, 64 b, 8 chunks), block 256 (4 waves), t-chunk = 256 steps
// (+64-step warmup for chunk>0). BARRIER-FREE, NO LDS: each wave owns 32 h and
// scans LIF in the MFMA C-layout (col=lane&15 -> h, row=lg*4+r -> t) with
// 4-way lane-group serialization; v-carry moves lg->lg+1 via __shfl, final
// state broadcast from lg=3. Digit recombine = R5's exact path (absmax 0).
// Spikes stored as bytes s2b[t][b][h] -- the i8 A-operand format for K34.
// 1-deep A prefetch; final prefetch overruns into dp region (valid ws, unused).
__global__ __launch_bounds__(256, 4) void k2_mfma_lif2(
    const unsigned char* __restrict__ s1, const signed char* __restrict__ dp,
    unsigned char* __restrict__ s2b) {
  const int tid  = threadIdx.x;
  const int lane = tid & 63;
  const int wv   = tid >> 6;        // 0..3
  const int hg   = blockIdx.x;      // 0..1
  const int b    = blockIdx.y;      // 0..63
  const int chunk= blockIdx.z;      // 0..7
  const int t0   = chunk * 256;
  const int nwarm= (chunk == 0) ? 0 : 4;      // warmup sub-chunks (x16 t)
  const int ts   = t0 - nwarm * 16;
  const int l15  = lane & 15;
  const int lg   = lane >> 4;       // 0..3 (k-group / t-row group)

  // B fragments (verified): wave's 32 h = hg*128 + wv*32 + n*16 + l15, n=0,1.
  // lane holds k = kc*64 + lg*16 + j -> 16 consecutive c bytes.
  v4i Bf[2][4][2];
#pragma unroll
  for (int n = 0; n < 2; ++n) {
    const int h = hg * 128 + wv * 32 + n * 16 + l15;
#pragma unroll
    for (int d = 0; d < 4; ++d)
#pragma unroll
      for (int kc = 0; kc < 2; ++kc)
        Bf[n][d][kc] = *(const v4i*)(dp + d * (HH * CC) + h * CC + kc * 64 + lg * 16);
  }

  // A (verified): lane reads s1 row m = tb + l15, bytes kc*64 + lg*16.
  const unsigned char* ap =
      s1 + ((size_t)(ts + l15) * BB + b) * CC + lg * 16;
  v4i Af0 = *(const v4i*)(ap);
  v4i Af1 = *(const v4i*)(ap + 64);
  ap += 16 * BB * CC;

  float v0 = 0.0f, v1 = 0.0f;       // LIF2 states (n=0,1) for this lane's h

  const int nsub = nwarm + 16;
  for (int s = 0; s < nsub; ++s) {
    const int tb = ts + s * 16;

    // prefetch next sub-chunk's A (overrun past t=2047 lands in dp region)
    v4i Pf0 = *(const v4i*)(ap);
    v4i Pf1 = *(const v4i*)(ap + 64);
    ap += 16 * BB * CC;

    float u0[4], u1[4];
#pragma unroll
    for (int n = 0; n < 2; ++n) {
      v4i a0 = {0, 0, 0, 0}, a1 = {0, 0, 0, 0}, a2 = {0, 0, 0, 0}, a3 = {0, 0, 0, 0};
      a0 = __builtin_amdgcn_mfma_i32_16x16x64_i8(Af0, Bf[n][0][0], a0, 0, 0, 0);
      a1 = __builtin_amdgcn_mfma_i32_16x16x64_i8(Af0, Bf[n][1][0], a1, 0, 0, 0);
      a2 = __builtin_amdgcn_mfma_i32_16x16x64_i8(Af0, Bf[n][2][0], a2, 0, 0, 0);
      a3 = __builtin_amdgcn_mfma_i32_16x16x64_i8(Af0, Bf[n][3][0], a3, 0, 0, 0);
      a0 = __builtin_amdgcn_mfma_i32_16x16x64_i8(Af1, Bf[n][0][1], a0, 0, 0, 0);
      a1 = __builtin_amdgcn_mfma_i32_16x16x64_i8(Af1, Bf[n][1][1], a1, 0, 0, 0);
      a2 = __builtin_amdgcn_mfma_i32_16x16x64_i8(Af1, Bf[n][2][1], a2, 0, 0, 0);
      a3 = __builtin_amdgcn_mfma_i32_16x16x64_i8(Af1, Bf[n][3][1], a3, 0, 0, 0);
#pragma unroll
      for (int r = 0; r < 4; ++r) {
        int hi = a3[r] * 256 + a2[r];             // exact, |.| < 2^24
        int lo = a1[r] * 256 + a0[r];
        float u = fmaf((float)hi, 0x1p-15f, (float)lo * 0x1p-31f);
        if (n == 0) u0[r] = u; else u1[r] = u;
      }
    }

    // LIF scan in MFMA layout: lg-group g handles t = tb + g*4 + r.
    unsigned sp0 = 0, sp1 = 0;
#pragma unroll
    for (int g = 0; g < 4; ++g) {
      if (lg == g) {
#pragma unroll
        for (int r = 0; r < 4; ++r) {
          v0 = fmaf(v0, 0.5f, u0[r]); bool a = (v0 >= 1.0f); if (a) v0 = 0.0f;
          sp0 |= (a ? 1u : 0u) << r;
          v1 = fmaf(v1, 0.5f, u1[r]); bool c = (v1 >= 1.0f); if (c) v1 = 0.0f;
          sp1 |= (c ? 1u : 0u) << r;
        }
      }
      if (g < 3) {   // carry handoff lg==g -> lg==g+1 (all lanes shuffle)
        float w0 = __shfl(v0, (lane - 16) & 63);
        float w1 = __shfl(v1, (lane - 16) & 63);
        if (lg == g + 1) { v0 = w0; v1 = w1; }
      }
    }
    // broadcast final state (lg==3) to all lanes for the next sub-chunk
    v0 = __shfl(v0, 48 + l15);
    v1 = __shfl(v1, 48 + l15);

    if (s >= nwarm) {                // wave-uniform
      size_t base = ((size_t)(tb + lg * 4) * BB + b) * 256 + hg * 128 + wv * 32 + l15;
#pragma unroll
      for (int r = 0; r < 4; ++r) {
        s2b[base + (size_t)r * (BB * 256)]      = (unsigned char)((sp0 >> r) & 1u);
        s2b[base + (size_t)r * (BB * 256) + 16] = (unsigned char)((sp1 >> r) & 1u);
      }
    }

    Af0 = Pf0; Af1 = Pf1;
  }
}

// ---------------- K34: fused MFMA-i8 (s2 @ W2^T) + LIF3 + count ----------------
// grid (64 b, 16 chunks), block 64 (1 wave). chunk = 128 t = 8 subs
// (+4 warmup subs for chunk>0). Per sub: A = spikes 16t x 256h bytes,
// B = W2 digit planes (nc=col=l15, padded rows zero), 16 MFMA (4 kc x 4 digits),
// exact digit recombine, in-register LIF3 scan (same lg-group scheme as K2),
// spike count accumulated; one atomicAdd per class at the end (exact dyadic).
__global__ __launch_bounds__(64, 4) void k34_gemm3_lif3(
    const unsigned char* __restrict__ s2b, const signed char* __restrict__ dp2,
    float* __restrict__ out) {
  const int lane = threadIdx.x;
  const int l15  = lane & 15;
  const int lg   = lane >> 4;
  const int b    = blockIdx.x;      // 0..63
  const int chunk= blockIdx.y;      // 0..15
  const int t0   = chunk * 128;
  const int nwarm= (chunk == 0) ? 0 : 4;
  const int ts   = t0 - nwarm * 16;

  v4i Bf[4][4];                     // [digit][kc]; col = l15 -> nc
#pragma unroll
  for (int d = 0; d < 4; ++d)
#pragma unroll
    for (int kc = 0; kc < 4; ++kc)
      Bf[d][kc] = *(const v4i*)(dp2 + d * (16 * HH) + l15 * HH + kc * 64 + lg * 16);

  const unsigned char* ap =
      s2b + ((size_t)(ts + l15) * BB + b) * 256 + lg * 16;
  v4i Af[4];
#pragma unroll
  for (int kc = 0; kc < 4; ++kc) Af[kc] = *(const v4i*)(ap + kc * 64);
  ap += 16 * BB * 256;

  float v = 0.0f, cnt = 0.0f;
  const int nsub = nwarm + 8;
  for (int s = 0; s < nsub; ++s) {
    v4i Pf[4];
#pragma unroll
    for (int kc = 0; kc < 4; ++kc) Pf[kc] = *(const v4i*)(ap + kc * 64);
    ap += 16 * BB * 256;

    v4i a0 = {0, 0, 0, 0}, a1 = {0, 0, 0, 0}, a2 = {0, 0, 0, 0}, a3 = {0, 0, 0, 0};
#pragma unroll
    for (int kc = 0; kc < 4; ++kc) {
      a0 = __builtin_amdgcn_mfma_i32_16x16x64_i8(Af[kc], Bf[0][kc], a0, 0, 0, 0);
      a1 = __builtin_amdgcn_mfma_i32_16x16x64_i8(Af[kc], Bf[1][kc], a1, 0, 0, 0);
      a2 = __builtin_amdgcn_mfma_i32_16x16x64_i8(Af[kc], Bf[2][kc], a2, 0, 0, 0);
      a3 = __builtin_amdgcn_mfma_i32_16x16x64_i8(Af[kc], Bf[3][kc], a3, 0, 0, 0);
    }

    float u[4];
#pragma unroll
    for (int r = 0; r < 4; ++r) {
      int hi = a3[r] * 256 + a2[r];
      int lo = a1[r] * 256 + a0[r];
      u[r] = fmaf((float)hi, 0x1p-15f, (float)lo * 0x1p-31f);
    }

    bool commit = (s >= nwarm);
#pragma unroll
    for (int g = 0; g < 4; ++g) {
      if (lg == g) {
#pragma unroll
        for (int r = 0; r < 4; ++r) {
          v = fmaf(v, 0.5f, u[r]); bool a = (v >= 1.0f); if (a) v = 0.0f;
          if (a && commit) cnt += 1.0f;
        }
      }
      if (g < 3) {
        float w = __shfl(v, (lane - 16) & 63);
        if (lg == g + 1) v = w;
      }
    }
    v = __shfl(v, 48 + l15);

#pragma unroll
    for (int kc = 0; kc < 4; ++kc) Af[kc] = Pf[kc];
  }

  // reduce cnt over lg (xor butterfly over lane bits 4,5)
  cnt += __shfl_xor(cnt, 16);
  cnt += __shfl_xor(cnt, 32);
  if (lane < NCLS)
    atomicAdd(&out[b * NCLS + lane], cnt * (1.0f / 2048.0f));  // exact dyadic
}

extern "C" void kernel_launch(void* const* d_in, const int* in_sizes, int n_in,
                              void* d_out, int out_size, void* d_ws, size_t ws_size,
                              hipStream_t stream) {
  const float* x  = (const float*)d_in[0];   // [64,2048]
  const float* cw = (const float*)d_in[1];   // [128,1,7]
  const float* W1 = (const float*)d_in[2];   // [256,128]
  const float* W2 = (const float*)d_in[3];   // [10,256]
  float* out = (float*)d_out;                // [64,10]

  char* ws = (char*)d_ws;
  unsigned char* s1  = (unsigned char*)(ws + S1_OFF);
  signed char*   dp  = (signed char*)(ws + DP_OFF);
  signed char*   dp2 = (signed char*)(ws + DP2_OFF);
  unsigned char* s2b = (unsigned char*)(ws + S2B_OFF);

  hipMemsetAsync(d_out, 0, 64 * NCLS * sizeof(float), stream);

  k0_digits<<<dim3(HH + 16), 128, 0, stream>>>(W1, W2, dp, dp2);
  k1_conv_lif1<<<dim3(16, 64), 128, 0, stream>>>(x, cw, s1);
  k2_mfma_lif2<<<dim3(2, 64, 8), 256, 0, stream>>>(s1, dp, s2b);
  k34_gemm3_lif3<<<dim3(64, 16), 64, 0, stream>>>(s2b, dp2, out);
  (void)in_sizes; (void)n_in; (void)out_size; (void)ws_size;
}